// Round 2
// baseline (497.408 us; speedup 1.0000x reference)
//
#include <hip/hip_runtime.h>
#include <hip/hip_bf16.h>
#include <math.h>

// Problem constants
constexpr int NN = 50000;   // nodes
constexpr int NE = 800000;  // edges (without self loops)
constexpr int ET = NE + NN; // edges + self loops
constexpr int FH = 128;     // HEADS*HID = feature width (also IN_CH)
constexpr int NHEAD = 4;
constexpr int NG = 64;      // graphs
constexpr int OC = 10;      // out channels
constexpr int NB = (NN + 255) / 256; // 196 scan blocks

// partition-owner CSR build: CPART blocks, each owns CPSZ nodes, LDS-only
// atomics (device-scope atomics write through to memory side on gfx950 --
// round-1 WRITE_SIZE showed ~25MB of atomic write-through for 800K adds).
constexpr int CPART = 64;
constexpr int CPSZ = (NN + CPART - 1) / CPART; // 782 nodes/partition (3.1KB LDS)

// W^T pack: [128 n][136 k] ushort, padded to 136 for LDS bank stagger
constexpr int WKP = 136;
constexpr int WPLANE = 128 * WKP;   // ushorts per plane (hi or lo)

constexpr int GEMM1_GRID = (NN + 255) / 256;  // 196 blocks x 1024 thr (16 waves)
constexpr int GEMM2_GRID = (NN + 63) / 64;    // 782 blocks x 256 thr

typedef __attribute__((ext_vector_type(8))) short short8;
typedef __attribute__((ext_vector_type(4))) float f32x4;

__device__ inline ushort f2bf_bits(float f) {
    union { __hip_bfloat16 h; ushort u; } c;
    c.h = __float2bfloat16(f);
    return c.u;
}

// ---------------------------------------------------------------------------
// W split-precision pack (both layers). wt layout: l1 hi | l1 lo | l2 hi | l2 lo
// ---------------------------------------------------------------------------
__global__ __launch_bounds__(256) void pack_kernel(const float* __restrict__ W1,
                                                   const float* __restrict__ W2,
                                                   ushort* __restrict__ wt) {
    int idx = blockIdx.x * 256 + threadIdx.x; // 0..32767
    int layer = idx >> 14;
    int k = (idx >> 7) & 127;
    int n = idx & 127;
    const float* W = layer ? W2 : W1;
    float f = W[k * 128 + n];
    ushort hb = f2bf_bits(f);
    union { ushort u; __hip_bfloat16 h; } c; c.u = hb;
    float lo = f - __bfloat162float(c.h);
    ushort* base = wt + layer * 2 * WPLANE;
    base[n * WKP + k] = hb;
    base[WPLANE + n * WKP + k] = f2bf_bits(lo);
}

// ---------------------------------------------------------------------------
// MFMA GEMM + attention epilogue (per-wave; wave/row0 set by caller).
// C/D layout: col=lane&15, row=quad*4+reg.
// ---------------------------------------------------------------------------
#define GEMM_EPILOGUE()                                                          \
    float as_[8], ad_[8];                                                        \
    _Pragma("unroll")                                                            \
    for (int t = 0; t < 8; ++t) {                                                \
        as_[t] = att_s[t * 16 + l16];                                            \
        ad_[t] = att_d[t * 16 + l16];                                            \
    }                                                                            \
    float hs[4][4], hd[4][4];                                                    \
    _Pragma("unroll")                                                            \
    for (int r = 0; r < 4; ++r) {                                                \
        int grow = row0 + quad * 4 + r;                                          \
        bool okr = (grow < NN);                                                  \
        _Pragma("unroll")                                                        \
        for (int h = 0; h < 4; ++h) {                                            \
            hs[r][h] = acc[2*h][r] * as_[2*h] + acc[2*h+1][r] * as_[2*h+1];      \
            hd[r][h] = acc[2*h][r] * ad_[2*h] + acc[2*h+1][r] * ad_[2*h+1];      \
        }                                                                        \
        if (okr) {                                                               \
            _Pragma("unroll")                                                    \
            for (int t = 0; t < 8; ++t)                                          \
                Hb[(size_t)grow * FH + t * 16 + l16] = __float2bfloat16(acc[t][r]); \
        }                                                                        \
    }                                                                            \
    _Pragma("unroll")                                                            \
    for (int o = 1; o < 16; o <<= 1) {                                           \
        _Pragma("unroll")                                                        \
        for (int r = 0; r < 4; ++r)                                              \
            _Pragma("unroll")                                                    \
            for (int h = 0; h < 4; ++h) {                                        \
                hs[r][h] += __shfl_xor(hs[r][h], o);                             \
                hd[r][h] += __shfl_xor(hd[r][h], o);                             \
            }                                                                    \
    }                                                                            \
    if (l16 == 0) {                                                              \
        _Pragma("unroll")                                                        \
        for (int r = 0; r < 4; ++r) {                                            \
            int grow = row0 + quad * 4 + r;                                      \
            if (grow < NN) {                                                     \
                *(float4*)&a_src[grow * NHEAD] = make_float4(hs[r][0], hs[r][1], hs[r][2], hs[r][3]); \
                *(float4*)&a_dst[grow * NHEAD] = make_float4(hd[r][0], hd[r][1], hd[r][2], hd[r][3]); \
            }                                                                    \
        }                                                                        \
    }

// ---------------------------------------------------------------------------
// Fused dispatch (1024 threads): blocks [0,CPART) = partition-owner degree
// count with LDS histogram (zero global atomics; plain stores to counts);
// blocks [CPART, CPART+GEMM1_GRID) = layer-1 GEMM, 16 waves x 16 rows.
// ---------------------------------------------------------------------------
__global__ __launch_bounds__(1024) void fused_count_gemm_kernel(
    const int* __restrict__ ei, int* __restrict__ counts,
    const float* __restrict__ A, const ushort* __restrict__ wt,
    const float* __restrict__ att_s, const float* __restrict__ att_d,
    __hip_bfloat16* __restrict__ Hb, float* __restrict__ a_src, float* __restrict__ a_dst)
{
    __shared__ ushort Wlds[2 * WPLANE];
    const int tid = threadIdx.x;

    if (blockIdx.x < CPART) {
        int* hist = (int*)Wlds;
        const int lo = blockIdx.x * CPSZ;
        const int hi = (lo + CPSZ < NN) ? lo + CPSZ : NN;
        const int psz = hi - lo;
        for (int i = tid; i < psz; i += 1024) hist[i] = 0;
        __syncthreads();
        const int4* dp = (const int4*)(ei + NE);
        for (int k = tid; k < NE / 4; k += 1024) {
            int4 d4 = dp[k];
            int d[4] = {d4.x, d4.y, d4.z, d4.w};
#pragma unroll
            for (int j = 0; j < 4; ++j) {
                int v = d[j] - lo;
                if ((unsigned)v < (unsigned)psz) atomicAdd(&hist[v], 1);
            }
        }
        __syncthreads();
        for (int i = tid; i < psz; i += 1024) counts[lo + i] = hist[i];
        return;
    }

    // ---- layer-1 GEMM (f32 input, split precision), 16 waves ----
    {
        const uint4* s = (const uint4*)wt;
        uint4* d = (uint4*)Wlds;
        for (int i = tid; i < 2 * WPLANE / 8; i += 1024) d[i] = s[i];
    }
    __syncthreads();

    const int wave = tid >> 6;         // 0..15
    const int lane = tid & 63;
    const int quad = lane >> 4;
    const int l16 = lane & 15;
    const int row0 = (blockIdx.x - CPART) * 256 + wave * 16;

    f32x4 acc[8];
#pragma unroll
    for (int t = 0; t < 8; ++t) acc[t] = (f32x4){0.f, 0.f, 0.f, 0.f};

    int arow = row0 + l16; if (arow >= NN) arow = NN - 1;
    const float* ap = A + (size_t)arow * FH + quad * 8;

#pragma unroll
    for (int kc = 0; kc < 4; ++kc) {
        float4 x0 = *(const float4*)(ap + kc * 32);
        float4 x1 = *(const float4*)(ap + kc * 32 + 4);
        float av[8] = {x0.x, x0.y, x0.z, x0.w, x1.x, x1.y, x1.z, x1.w};
        short8 ah, al;
#pragma unroll
        for (int j = 0; j < 8; ++j) {
            ushort hb = f2bf_bits(av[j]);
            union { ushort u; __hip_bfloat16 h; } c; c.u = hb;
            float lo = av[j] - __bfloat162float(c.h);
            ah[j] = (short)hb;
            al[j] = (short)f2bf_bits(lo);
        }
        const int kof = kc * 32 + quad * 8;
#pragma unroll
        for (int t = 0; t < 8; ++t) {
            const ushort* wp = &Wlds[(t * 16 + l16) * WKP + kof];
            short8 wh = *(const short8*)wp;
            short8 wl = *(const short8*)(wp + WPLANE);
            acc[t] = __builtin_amdgcn_mfma_f32_16x16x32_bf16(ah, wh, acc[t], 0, 0, 0);
            acc[t] = __builtin_amdgcn_mfma_f32_16x16x32_bf16(al, wh, acc[t], 0, 0, 0);
            acc[t] = __builtin_amdgcn_mfma_f32_16x16x32_bf16(ah, wl, acc[t], 0, 0, 0);
        }
    }
    GEMM_EPILOGUE()
}

__global__ __launch_bounds__(256) void partial_kernel(const int* __restrict__ counts,
                                                      int* __restrict__ bsum) {
    __shared__ int sd[256];
    const int t = threadIdx.x, n = blockIdx.x * 256 + t;
    int v = (n < NN) ? counts[n] + 1 : 0;
    sd[t] = v; __syncthreads();
#pragma unroll
    for (int o = 128; o > 0; o >>= 1) {
        if (t < o) sd[t] += sd[t + o];
        __syncthreads();
    }
    if (t == 0) bsum[blockIdx.x] = sd[0];
}

// write_offs with inlined block-sum scan; also writes the self-loop entry
// (slot ex+deg, never touched by scatter since LDS cursors start at offs).
__global__ __launch_bounds__(256) void write_offs_kernel(const int* __restrict__ counts,
                                                         const int* __restrict__ bsum,
                                                         int* __restrict__ offs,
                                                         int* __restrict__ csrc) {
    __shared__ int sd[256];
    __shared__ int bprefix;
    const int t = threadIdx.x, n = blockIdx.x * 256 + t;
    int bv = (t < NB) ? bsum[t] : 0;
    sd[t] = bv; __syncthreads();
#pragma unroll
    for (int o = 1; o < 256; o <<= 1) {
        int u = (t >= o) ? sd[t - o] : 0;
        __syncthreads();
        sd[t] += u;
        __syncthreads();
    }
    if (t == (int)blockIdx.x) bprefix = sd[t] - bv;
    __syncthreads();
    const int bpre = bprefix;
    __syncthreads();
    int v = (n < NN) ? counts[n] + 1 : 0;
    sd[t] = v; __syncthreads();
#pragma unroll
    for (int o = 1; o < 256; o <<= 1) {
        int u = (t >= o) ? sd[t - o] : 0;
        __syncthreads();
        sd[t] += u;
        __syncthreads();
    }
    int ex = sd[t] - v + bpre;
    if (n < NN) {
        offs[n] = ex;
        csrc[ex + v - 1] = n;   // self loop at end of the node's range
    }
    if (n == NN - 1) offs[NN] = ex + v; // == ET
}

// ---------------------------------------------------------------------------
// Partition-owner scatter: cursors live in LDS (seeded from offs), position
// via LDS atomicAdd, csrc written with plain stores. Zero global atomics.
// ---------------------------------------------------------------------------
__global__ __launch_bounds__(1024) void scatter_kernel(const int* __restrict__ ei,
                                                       const int* __restrict__ offs,
                                                       int* __restrict__ csrc) {
    __shared__ int cur[CPSZ];
    const int tid = threadIdx.x;
    const int lo = blockIdx.x * CPSZ;
    const int hi = (lo + CPSZ < NN) ? lo + CPSZ : NN;
    const int psz = hi - lo;
    for (int i = tid; i < psz; i += 1024) cur[i] = offs[lo + i];
    __syncthreads();
    const int4* dp = (const int4*)(ei + NE);
    for (int k = tid; k < NE / 4; k += 1024) {
        int4 d4 = dp[k];
        int d[4] = {d4.x, d4.y, d4.z, d4.w};
        const int e0 = 4 * k;
#pragma unroll
        for (int j = 0; j < 4; ++j) {
            int v = d[j] - lo;
            if ((unsigned)v < (unsigned)psz) {
                int pos = atomicAdd(&cur[v], 1);
                csrc[pos] = ei[e0 + j];
            }
        }
    }
}

__global__ __launch_bounds__(256) void gemm_att_bf16_kernel(
    const __hip_bfloat16* __restrict__ A, const ushort* __restrict__ wt,
    const float* __restrict__ att_s, const float* __restrict__ att_d,
    __hip_bfloat16* __restrict__ Hb, float* __restrict__ a_src, float* __restrict__ a_dst)
{
    __shared__ ushort Wlds[2 * WPLANE];
    const int tid = threadIdx.x;
    {
        const uint4* s = (const uint4*)wt;
        uint4* d = (uint4*)Wlds;
        for (int i = tid; i < 2 * WPLANE / 8; i += 256) d[i] = s[i];
    }
    __syncthreads();

    const int wave = tid >> 6;
    const int lane = tid & 63;
    const int quad = lane >> 4;
    const int l16 = lane & 15;
    const int row0 = blockIdx.x * 64 + wave * 16;

    f32x4 acc[8];
#pragma unroll
    for (int t = 0; t < 8; ++t) acc[t] = (f32x4){0.f, 0.f, 0.f, 0.f};

    int arow = row0 + l16; if (arow >= NN) arow = NN - 1;
    const __hip_bfloat16* ap = A + (size_t)arow * FH + quad * 8;

#pragma unroll
    for (int kc = 0; kc < 4; ++kc) {
        short8 ah = *(const short8*)(ap + kc * 32);
        const int kof = kc * 32 + quad * 8;
#pragma unroll
        for (int t = 0; t < 8; ++t) {
            const ushort* wp = &Wlds[(t * 16 + l16) * WKP + kof];
            short8 wh = *(const short8*)wp;
            short8 wl = *(const short8*)(wp + WPLANE);
            acc[t] = __builtin_amdgcn_mfma_f32_16x16x32_bf16(ah, wh, acc[t], 0, 0, 0);
            acc[t] = __builtin_amdgcn_mfma_f32_16x16x32_bf16(ah, wl, acc[t], 0, 0, 0);
        }
    }
    GEMM_EPILOGUE()
}

// ---------------------------------------------------------------------------
// Per-node aggregation, one wave per node, producer/consumer over 64-edge
// chunks.
// ---------------------------------------------------------------------------
__global__ __launch_bounds__(256) void gat_agg_kernel(
    const __hip_bfloat16* __restrict__ Hb, const float* __restrict__ asrc,
    const float* __restrict__ adst, const int* __restrict__ offs,
    const int* __restrict__ csrc, const float* __restrict__ bias,
    __hip_bfloat16* __restrict__ out)
{
    __shared__ float2 wbuf[4][4][65];
    const int wid = threadIdx.x >> 6;
    const int lane = threadIdx.x & 63;
    const int n = blockIdx.x * 4 + wid;
    if (n >= NN) return;

    const int beg = offs[n], end = offs[n + 1];
    const int hB = lane & 3;
    const int eslot = lane >> 2;
    const float adB = adst[n * NHEAD + hB];
    float2* wrow = wbuf[wid][hB];
    const int es = lane >> 4;
    const int fs = lane & 15;
    const int hC = fs >> 2;
    const int f8 = fs * 8;
    const float2* crow = wbuf[wid][hC];

    float d = 0.f;
    float acc[8];
#pragma unroll
    for (int i = 0; i < 8; ++i) acc[i] = 0.f;

    for (int cs = beg; cs < end; cs += 64) {
        int ce = end - cs; if (ce > 64) ce = 64;
        for (int k = eslot; k < ce; k += 16) {
            int s = csrc[cs + k];
            float e = asrc[s * NHEAD + hB] + adB;
            e = e > 0.f ? e : 0.2f * e;
            float w = __expf(e);
            d += w;
            wrow[k] = make_float2(w, __int_as_float(s));
        }
        __asm__ volatile("s_waitcnt lgkmcnt(0)" ::: "memory");
        const int n8 = (ce + 7) >> 3;
        for (int p = 0; p < n8; ++p) {
            int eA = 8 * p + es;
            int eB = eA + 4;
            float2 wsA = crow[eA < ce ? eA : 0];
            float2 wsB = crow[eB < ce ? eB : 0];
            float wA = eA < ce ? wsA.x : 0.f;
            float wB = eB < ce ? wsB.x : 0.f;
            int sA = __float_as_int(wsA.y);
            int sB = __float_as_int(wsB.y);
            union { uint4 u; __hip_bfloat162 b[4]; } cvA, cvB;
            cvA.u = *(const uint4*)&Hb[(size_t)sA * FH + f8];
            cvB.u = *(const uint4*)&Hb[(size_t)sB * FH + f8];
#pragma unroll
            for (int i = 0; i < 4; ++i) {
                float2 hA = __bfloat1622float2(cvA.b[i]);
                float2 hB2 = __bfloat1622float2(cvB.b[i]);
                acc[2 * i]     = fmaf(wA, hA.x, acc[2 * i]);
                acc[2 * i + 1] = fmaf(wA, hA.y, acc[2 * i + 1]);
                acc[2 * i]     = fmaf(wB, hB2.x, acc[2 * i]);
                acc[2 * i + 1] = fmaf(wB, hB2.y, acc[2 * i + 1]);
            }
        }
    }
#pragma unroll
    for (int o = 4; o < 64; o <<= 1) d += __shfl_xor(d, o);
#pragma unroll
    for (int i = 0; i < 8; ++i) {
        acc[i] += __shfl_xor(acc[i], 16);
        acc[i] += __shfl_xor(acc[i], 32);
    }
    const float inv = 1.0f / __shfl(d, hC);
    if (es == 0) {
        union { ushort u8[8]; uint4 u; } pk;
#pragma unroll
        for (int i = 0; i < 8; ++i) {
            float v = fmaxf(fmaf(acc[i], inv, bias[f8 + i]), 0.f);
            pk.u8[i] = f2bf_bits(v);
        }
        *(uint4*)&out[(size_t)n * FH + f8] = pk.u;
    }
}

// ---------------------------------------------------------------------------
// Mean pool: one block per graph (batch sorted -> boundaries via binary
// search), LDS tree-reduce, plain stores. Zero atomics, no memset needed.
// ---------------------------------------------------------------------------
__global__ __launch_bounds__(256) void pool_kernel(
    const __hip_bfloat16* __restrict__ X, const int* __restrict__ batch,
    float* __restrict__ sums, int* __restrict__ cnts)
{
    const int g = blockIdx.x;
    const int t = threadIdx.x;
    // lower_bound(batch, g) and lower_bound(batch, g+1)
    int a = 0, b = NN;
    while (a < b) { int m = (a + b) >> 1; if (batch[m] < g) a = m + 1; else b = m; }
    const int gs = a;
    b = NN;
    while (a < b) { int m = (a + b) >> 1; if (batch[m] <= g) a = m + 1; else b = m; }
    const int ge = a;

    const int rg = t >> 4;       // row group 0..15
    const int l16 = t & 15;      // 16B feature slot
    float acc[8];
#pragma unroll
    for (int i = 0; i < 8; ++i) acc[i] = 0.f;
    for (int r = gs + rg; r < ge; r += 16) {
        union { uint4 u; __hip_bfloat162 bb[4]; } cv;
        cv.u = *(const uint4*)&X[(size_t)r * FH + l16 * 8];
#pragma unroll
        for (int i = 0; i < 4; ++i) {
            float2 f = __bfloat1622float2(cv.bb[i]);
            acc[2 * i]     += f.x;
            acc[2 * i + 1] += f.y;
        }
    }
    __shared__ float red[16][128];
#pragma unroll
    for (int i = 0; i < 8; ++i) red[rg][l16 * 8 + i] = acc[i];
    __syncthreads();
    if (t < 128) {
        float s = 0.f;
#pragma unroll
        for (int j = 0; j < 16; ++j) s += red[j][t];
        sums[g * FH + t] = s;
    }
    if (t == 0) cnts[g] = ge - gs;
}

__global__ void final_kernel(const float* __restrict__ sums, const int* __restrict__ cnts,
                             const float* __restrict__ wl, const float* __restrict__ bl,
                             float* __restrict__ out)
{
    const int t = threadIdx.x;
    if (t >= NG * OC) return;
    const int g = t / OC, o = t % OC;
    float invc = 1.0f / fmaxf((float)cnts[g], 1.0f);
    float acc = 0.f;
    for (int k = 0; k < FH; ++k)
        acc = fmaf(sums[g * FH + k], wl[k * OC + o], acc);
    out[t] = acc * invc + bl[o];
}

// ---------------------------------------------------------------------------
extern "C" void kernel_launch(void* const* d_in, const int* in_sizes, int n_in,
                              void* d_out, int out_size, void* d_ws, size_t ws_size,
                              hipStream_t stream) {
    const float* x       = (const float*)d_in[0];
    const int*   ei      = (const int*)d_in[1];   // [2, NE]
    const int*   batch   = (const int*)d_in[2];
    const float* W1      = (const float*)d_in[3];
    const float* as1     = (const float*)d_in[4];
    const float* ad1     = (const float*)d_in[5];
    const float* b1      = (const float*)d_in[6];
    const float* W2      = (const float*)d_in[7];
    const float* as2     = (const float*)d_in[8];
    const float* ad2     = (const float*)d_in[9];
    const float* b2      = (const float*)d_in[10];
    const float* wlin    = (const float*)d_in[11];
    const float* blin    = (const float*)d_in[12];
    float* out = (float*)d_out;

    // workspace layout
    __hip_bfloat16* hbuf = (__hip_bfloat16*)d_ws;        // NN*FH bf16 (gemm out)
    __hip_bfloat16* abuf = hbuf + (size_t)NN * FH;       // NN*FH bf16 (agg out)
    float* asrc  = (float*)(abuf + (size_t)NN * FH);     // NN*4
    float* adst  = asrc + (size_t)NN * NHEAD;
    float* sums  = adst + (size_t)NN * NHEAD; // NG*FH
    int*   cnts  = (int*)(sums + NG * FH);    // NG
    int* counts  = cnts + NG;                 // NN
    int* offs    = counts + NN;               // NN+1
    int* csrc    = offs + NN + 1;             // ET
    int* bsum    = csrc + ET;                 // NB
    ushort* wt   = (ushort*)(((uintptr_t)(bsum + NB) + 15) & ~(uintptr_t)15); // 4*WPLANE

    // No memset: counts/sums/cnts are fully plain-stored each iteration.

    // W pack first (fused kernel's gemm blocks read planes 0,1)
    pack_kernel<<<128, 256, 0, stream>>>(W1, W2, wt);

    // Fused: partition-owner degree count + layer-1 GEMM (one dispatch)
    fused_count_gemm_kernel<<<CPART + GEMM1_GRID, 1024, 0, stream>>>(
        ei, counts, x, wt, as1, ad1, hbuf, asrc, adst);

    partial_kernel<<<NB, 256, 0, stream>>>(counts, bsum);
    write_offs_kernel<<<NB, 256, 0, stream>>>(counts, bsum, offs, csrc);
    scatter_kernel<<<CPART, 1024, 0, stream>>>(ei, offs, csrc);

    const int agg_grid = (NN + 3) / 4;

    // Layer 1 aggregation (gemm already done in fused dispatch)
    gat_agg_kernel<<<agg_grid, 256, 0, stream>>>(hbuf, asrc, adst, offs, csrc, b1, abuf);
    // Layer 2
    gemm_att_bf16_kernel<<<GEMM2_GRID, 256, 0, stream>>>(abuf, wt + 2 * WPLANE, as2, ad2, hbuf, asrc, adst);
    gat_agg_kernel<<<agg_grid, 256, 0, stream>>>(hbuf, asrc, adst, offs, csrc, b2, abuf);

    // Pool + final linear
    pool_kernel<<<NG, 256, 0, stream>>>(abuf, batch, sums, cnts);
    final_kernel<<<1, NG * OC, 0, stream>>>(sums, cnts, wlin, blin, out);
}

// Round 3
// 253.151 us; speedup vs baseline: 1.9649x; 1.9649x over previous
//
#include <hip/hip_runtime.h>
#include <hip/hip_bf16.h>
#include <math.h>

// Problem constants
constexpr int NN = 50000;   // nodes
constexpr int NE = 800000;  // edges (without self loops)
constexpr int ET = NE + NN; // edges + self loops
constexpr int FH = 128;     // HEADS*HID = feature width (also IN_CH)
constexpr int NHEAD = 4;
constexpr int NG = 64;      // graphs
constexpr int OC = 10;      // out channels

// Multisplit CSR build: buckets of 256 nodes (bucket = dst >> 8).
// Zero global atomics anywhere in the pipeline (round-1 counters showed
// ~32B memory-side write-through per global atomic; round-2 showed the
// 64-block partition-owner scan is latency-doomed). Multisplit keeps
// per-block work proportional to E/blocks and uses only plain stores.
constexpr int NBK = (NN + 255) >> 8;   // 196 buckets
constexpr int EPB = 4000;              // edges per hist/scatter block
constexpr int HBLK = NE / EPB;         // 200 blocks

// W^T pack: [128 n][136 k] ushort, padded to 136 for LDS bank stagger
constexpr int WKP = 136;
constexpr int WPLANE = 128 * WKP;   // ushorts per plane (hi or lo)

constexpr int GEMM1_GRID = (NN + 255) / 256;  // 196 blocks x 1024 thr (16 waves)
constexpr int GEMM2_GRID = (NN + 63) / 64;    // 782 blocks x 256 thr

typedef __attribute__((ext_vector_type(8))) short short8;
typedef __attribute__((ext_vector_type(4))) float f32x4;

__device__ inline ushort f2bf_bits(float f) {
    union { __hip_bfloat16 h; ushort u; } c;
    c.h = __float2bfloat16(f);
    return c.u;
}

// ---------------------------------------------------------------------------
// W split-precision pack (both layers). wt layout: l1 hi | l1 lo | l2 hi | l2 lo
// ---------------------------------------------------------------------------
__global__ __launch_bounds__(256) void pack_kernel(const float* __restrict__ W1,
                                                   const float* __restrict__ W2,
                                                   ushort* __restrict__ wt) {
    int idx = blockIdx.x * 256 + threadIdx.x; // 0..32767
    int layer = idx >> 14;
    int k = (idx >> 7) & 127;
    int n = idx & 127;
    const float* W = layer ? W2 : W1;
    float f = W[k * 128 + n];
    ushort hb = f2bf_bits(f);
    union { ushort u; __hip_bfloat16 h; } c; c.u = hb;
    float lo = f - __bfloat162float(c.h);
    ushort* base = wt + layer * 2 * WPLANE;
    base[n * WKP + k] = hb;
    base[WPLANE + n * WKP + k] = f2bf_bits(lo);
}

// ---------------------------------------------------------------------------
// MFMA GEMM + attention epilogue (per-wave; wave/row0 set by caller).
// C/D layout: col=lane&15, row=quad*4+reg.
// ---------------------------------------------------------------------------
#define GEMM_EPILOGUE()                                                          \
    float as_[8], ad_[8];                                                        \
    _Pragma("unroll")                                                            \
    for (int t = 0; t < 8; ++t) {                                                \
        as_[t] = att_s[t * 16 + l16];                                            \
        ad_[t] = att_d[t * 16 + l16];                                            \
    }                                                                            \
    float hs[4][4], hd[4][4];                                                    \
    _Pragma("unroll")                                                            \
    for (int r = 0; r < 4; ++r) {                                                \
        int grow = row0 + quad * 4 + r;                                          \
        bool okr = (grow < NN);                                                  \
        _Pragma("unroll")                                                        \
        for (int h = 0; h < 4; ++h) {                                            \
            hs[r][h] = acc[2*h][r] * as_[2*h] + acc[2*h+1][r] * as_[2*h+1];      \
            hd[r][h] = acc[2*h][r] * ad_[2*h] + acc[2*h+1][r] * ad_[2*h+1];      \
        }                                                                        \
        if (okr) {                                                               \
            _Pragma("unroll")                                                    \
            for (int t = 0; t < 8; ++t)                                          \
                Hb[(size_t)grow * FH + t * 16 + l16] = __float2bfloat16(acc[t][r]); \
        }                                                                        \
    }                                                                            \
    _Pragma("unroll")                                                            \
    for (int o = 1; o < 16; o <<= 1) {                                           \
        _Pragma("unroll")                                                        \
        for (int r = 0; r < 4; ++r)                                              \
            _Pragma("unroll")                                                    \
            for (int h = 0; h < 4; ++h) {                                        \
                hs[r][h] += __shfl_xor(hs[r][h], o);                             \
                hd[r][h] += __shfl_xor(hd[r][h], o);                             \
            }                                                                    \
    }                                                                            \
    if (l16 == 0) {                                                              \
        _Pragma("unroll")                                                        \
        for (int r = 0; r < 4; ++r) {                                            \
            int grow = row0 + quad * 4 + r;                                      \
            if (grow < NN) {                                                     \
                *(float4*)&a_src[grow * NHEAD] = make_float4(hs[r][0], hs[r][1], hs[r][2], hs[r][3]); \
                *(float4*)&a_dst[grow * NHEAD] = make_float4(hd[r][0], hd[r][1], hd[r][2], hd[r][3]); \
            }                                                                    \
        }                                                                        \
    }

// ---------------------------------------------------------------------------
// Fused dispatch (1024 threads):
//  blocks [0, GEMM1_GRID): layer-1 GEMM (f32 input, split precision), 16 waves
//  blocks [GEMM1_GRID, +HBLK): per-block bucket histogram (LDS atomics only,
//    plain stores to blockHist[bucket][blk])
// ---------------------------------------------------------------------------
__global__ __launch_bounds__(1024) void fused_gemm_hist_kernel(
    const int* __restrict__ ei, int* __restrict__ blockHist,
    const float* __restrict__ A, const ushort* __restrict__ wt,
    const float* __restrict__ att_s, const float* __restrict__ att_d,
    __hip_bfloat16* __restrict__ Hb, float* __restrict__ a_src, float* __restrict__ a_dst)
{
    __shared__ ushort Wlds[2 * WPLANE];
    const int tid = threadIdx.x;

    if (blockIdx.x >= GEMM1_GRID) {
        const int blk = blockIdx.x - GEMM1_GRID;
        int* hist = (int*)Wlds;
        if (tid < NBK) hist[tid] = 0;
        __syncthreads();
        const int e0 = blk * EPB;
        if (tid < EPB / 4) {
            int4 d4 = *(const int4*)(ei + NE + e0 + 4 * tid);
            atomicAdd(&hist[d4.x >> 8], 1);
            atomicAdd(&hist[d4.y >> 8], 1);
            atomicAdd(&hist[d4.z >> 8], 1);
            atomicAdd(&hist[d4.w >> 8], 1);
        }
        __syncthreads();
        if (tid < NBK) blockHist[tid * HBLK + blk] = hist[tid];
        return;
    }

    // ---- layer-1 GEMM (f32 input, split precision), 16 waves ----
    {
        const uint4* s = (const uint4*)wt;
        uint4* d = (uint4*)Wlds;
        for (int i = tid; i < 2 * WPLANE / 8; i += 1024) d[i] = s[i];
    }
    __syncthreads();

    const int wave = tid >> 6;         // 0..15
    const int lane = tid & 63;
    const int quad = lane >> 4;
    const int l16 = lane & 15;
    const int row0 = blockIdx.x * 256 + wave * 16;

    f32x4 acc[8];
#pragma unroll
    for (int t = 0; t < 8; ++t) acc[t] = (f32x4){0.f, 0.f, 0.f, 0.f};

    int arow = row0 + l16; if (arow >= NN) arow = NN - 1;
    const float* ap = A + (size_t)arow * FH + quad * 8;

#pragma unroll
    for (int kc = 0; kc < 4; ++kc) {
        float4 x0 = *(const float4*)(ap + kc * 32);
        float4 x1 = *(const float4*)(ap + kc * 32 + 4);
        float av[8] = {x0.x, x0.y, x0.z, x0.w, x1.x, x1.y, x1.z, x1.w};
        short8 ah, al;
#pragma unroll
        for (int j = 0; j < 8; ++j) {
            ushort hb = f2bf_bits(av[j]);
            union { ushort u; __hip_bfloat16 h; } c; c.u = hb;
            float lo = av[j] - __bfloat162float(c.h);
            ah[j] = (short)hb;
            al[j] = (short)f2bf_bits(lo);
        }
        const int kof = kc * 32 + quad * 8;
#pragma unroll
        for (int t = 0; t < 8; ++t) {
            const ushort* wp = &Wlds[(t * 16 + l16) * WKP + kof];
            short8 wh = *(const short8*)wp;
            short8 wl = *(const short8*)(wp + WPLANE);
            acc[t] = __builtin_amdgcn_mfma_f32_16x16x32_bf16(ah, wh, acc[t], 0, 0, 0);
            acc[t] = __builtin_amdgcn_mfma_f32_16x16x32_bf16(al, wh, acc[t], 0, 0, 0);
            acc[t] = __builtin_amdgcn_mfma_f32_16x16x32_bf16(ah, wl, acc[t], 0, 0, 0);
        }
    }
    GEMM_EPILOGUE()
}

// ---------------------------------------------------------------------------
// Scan A: per-bucket exclusive scan over the HBLK=200 block counts (in place)
// + bucket totals. One block per bucket.
// ---------------------------------------------------------------------------
__global__ __launch_bounds__(256) void scanA_kernel(int* __restrict__ bh,
                                                    int* __restrict__ bsumB) {
    __shared__ int sd[256];
    const int b = blockIdx.x, t = threadIdx.x;
    int v = (t < HBLK) ? bh[b * HBLK + t] : 0;
    sd[t] = v; __syncthreads();
#pragma unroll
    for (int o = 1; o < 256; o <<= 1) {
        int u = (t >= o) ? sd[t - o] : 0;
        __syncthreads();
        sd[t] += u;
        __syncthreads();
    }
    if (t < HBLK) bh[b * HBLK + t] = sd[t] - v;   // exclusive within bucket
    if (t == 255) bsumB[b] = sd[255];
}

// Scan B: exclusive scan of the 196 bucket totals -> bucket edge bases.
__global__ __launch_bounds__(256) void scanB_kernel(const int* __restrict__ bsumB,
                                                    int* __restrict__ ebase,
                                                    int* __restrict__ offs) {
    __shared__ int sd[256];
    const int t = threadIdx.x;
    int v = (t < NBK) ? bsumB[t] : 0;
    sd[t] = v; __syncthreads();
#pragma unroll
    for (int o = 1; o < 256; o <<= 1) {
        int u = (t >= o) ? sd[t - o] : 0;
        __syncthreads();
        sd[t] += u;
        __syncthreads();
    }
    if (t < NBK) ebase[t] = sd[t] - v;
    if (t == NBK - 1) ebase[NBK] = sd[t];   // == NE
    if (t == 0) offs[NN] = ET;
}

// ---------------------------------------------------------------------------
// Bucket scatter: each block re-reads its EPB edges (src+dst, coalesced int4),
// places (src,dst) into its bucket region via LDS cursors seeded from the
// scanned histogram. Plain 8B stores; slots globally unique by construction.
// ---------------------------------------------------------------------------
__global__ __launch_bounds__(1024) void bucket_scatter_kernel(
    const int* __restrict__ ei, const int* __restrict__ bh,
    const int* __restrict__ ebase, int2* __restrict__ ebuf) {
    __shared__ int cur[NBK];
    const int tid = threadIdx.x;
    const int blk = blockIdx.x;
    for (int i = tid; i < NBK; i += 1024) cur[i] = ebase[i] + bh[i * HBLK + blk];
    __syncthreads();
    const int e0 = blk * EPB;
    if (tid < EPB / 4) {
        int4 d4 = *(const int4*)(ei + NE + e0 + 4 * tid);
        int4 s4 = *(const int4*)(ei + e0 + 4 * tid);
        int ds[4] = {d4.x, d4.y, d4.z, d4.w};
        int ss[4] = {s4.x, s4.y, s4.z, s4.w};
#pragma unroll
        for (int j = 0; j < 4; ++j) {
            int pos = atomicAdd(&cur[ds[j] >> 8], 1);
            ebuf[pos] = make_int2(ss[j], ds[j]);
        }
    }
}

// ---------------------------------------------------------------------------
// Per-bucket CSR finalize: one block per bucket (256 nodes, ~4K edges).
// count (LDS) -> scan (LDS) -> write offs + self loops -> place csrc.
// ---------------------------------------------------------------------------
__global__ __launch_bounds__(256) void bucket_csr_kernel(
    const int2* __restrict__ ebuf, const int* __restrict__ ebase,
    int* __restrict__ offs, int* __restrict__ csrc) {
    __shared__ int hist[256];
    __shared__ int sd[256];
    __shared__ int cur[256];
    const int b = blockIdx.x, t = threadIdx.x;
    const int lo = b << 8;
    int psz = NN - lo; if (psz > 256) psz = 256;
    const int e0 = ebase[b], e1 = ebase[b + 1];

    hist[t] = 0;
    __syncthreads();
    for (int k = e0 + t; k < e1; k += 256) {
        int2 e = ebuf[k];
        atomicAdd(&hist[e.y - lo], 1);
    }
    __syncthreads();
    const int d = hist[t];
    sd[t] = d; __syncthreads();
#pragma unroll
    for (int o = 1; o < 256; o <<= 1) {
        int u = (t >= o) ? sd[t - o] : 0;
        __syncthreads();
        sd[t] += u;
        __syncthreads();
    }
    const int ex = sd[t] - d;
    if (t < psz) {
        const int node = lo + t;
        const int o = e0 + ex + node;   // offs[n] = ebase[b] + exdeg + n
        offs[node] = o;
        cur[t] = o;
        csrc[o + d] = node;             // self loop at end of the node's range
    }
    __syncthreads();
    for (int k = e0 + t; k < e1; k += 256) {
        int2 e = ebuf[k];
        int pos = atomicAdd(&cur[e.y - lo], 1);
        csrc[pos] = e.x;
    }
}

__global__ __launch_bounds__(256) void gemm_att_bf16_kernel(
    const __hip_bfloat16* __restrict__ A, const ushort* __restrict__ wt,
    const float* __restrict__ att_s, const float* __restrict__ att_d,
    __hip_bfloat16* __restrict__ Hb, float* __restrict__ a_src, float* __restrict__ a_dst)
{
    __shared__ ushort Wlds[2 * WPLANE];
    const int tid = threadIdx.x;
    {
        const uint4* s = (const uint4*)wt;
        uint4* d = (uint4*)Wlds;
        for (int i = tid; i < 2 * WPLANE / 8; i += 256) d[i] = s[i];
    }
    __syncthreads();

    const int wave = tid >> 6;
    const int lane = tid & 63;
    const int quad = lane >> 4;
    const int l16 = lane & 15;
    const int row0 = blockIdx.x * 64 + wave * 16;

    f32x4 acc[8];
#pragma unroll
    for (int t = 0; t < 8; ++t) acc[t] = (f32x4){0.f, 0.f, 0.f, 0.f};

    int arow = row0 + l16; if (arow >= NN) arow = NN - 1;
    const __hip_bfloat16* ap = A + (size_t)arow * FH + quad * 8;

#pragma unroll
    for (int kc = 0; kc < 4; ++kc) {
        short8 ah = *(const short8*)(ap + kc * 32);
        const int kof = kc * 32 + quad * 8;
#pragma unroll
        for (int t = 0; t < 8; ++t) {
            const ushort* wp = &Wlds[(t * 16 + l16) * WKP + kof];
            short8 wh = *(const short8*)wp;
            short8 wl = *(const short8*)(wp + WPLANE);
            acc[t] = __builtin_amdgcn_mfma_f32_16x16x32_bf16(ah, wh, acc[t], 0, 0, 0);
            acc[t] = __builtin_amdgcn_mfma_f32_16x16x32_bf16(ah, wl, acc[t], 0, 0, 0);
        }
    }
    GEMM_EPILOGUE()
}

// ---------------------------------------------------------------------------
// Per-node aggregation, one wave per node, producer/consumer over 64-edge
// chunks.
// ---------------------------------------------------------------------------
__global__ __launch_bounds__(256) void gat_agg_kernel(
    const __hip_bfloat16* __restrict__ Hb, const float* __restrict__ asrc,
    const float* __restrict__ adst, const int* __restrict__ offs,
    const int* __restrict__ csrc, const float* __restrict__ bias,
    __hip_bfloat16* __restrict__ out)
{
    __shared__ float2 wbuf[4][4][65];
    const int wid = threadIdx.x >> 6;
    const int lane = threadIdx.x & 63;
    const int n = blockIdx.x * 4 + wid;
    if (n >= NN) return;

    const int beg = offs[n], end = offs[n + 1];
    const int hB = lane & 3;
    const int eslot = lane >> 2;
    const float adB = adst[n * NHEAD + hB];
    float2* wrow = wbuf[wid][hB];
    const int es = lane >> 4;
    const int fs = lane & 15;
    const int hC = fs >> 2;
    const int f8 = fs * 8;
    const float2* crow = wbuf[wid][hC];

    float d = 0.f;
    float acc[8];
#pragma unroll
    for (int i = 0; i < 8; ++i) acc[i] = 0.f;

    for (int cs = beg; cs < end; cs += 64) {
        int ce = end - cs; if (ce > 64) ce = 64;
        for (int k = eslot; k < ce; k += 16) {
            int s = csrc[cs + k];
            float e = asrc[s * NHEAD + hB] + adB;
            e = e > 0.f ? e : 0.2f * e;
            float w = __expf(e);
            d += w;
            wrow[k] = make_float2(w, __int_as_float(s));
        }
        __asm__ volatile("s_waitcnt lgkmcnt(0)" ::: "memory");
        const int n8 = (ce + 7) >> 3;
        for (int p = 0; p < n8; ++p) {
            int eA = 8 * p + es;
            int eB = eA + 4;
            float2 wsA = crow[eA < ce ? eA : 0];
            float2 wsB = crow[eB < ce ? eB : 0];
            float wA = eA < ce ? wsA.x : 0.f;
            float wB = eB < ce ? wsB.x : 0.f;
            int sA = __float_as_int(wsA.y);
            int sB = __float_as_int(wsB.y);
            union { uint4 u; __hip_bfloat162 b[4]; } cvA, cvB;
            cvA.u = *(const uint4*)&Hb[(size_t)sA * FH + f8];
            cvB.u = *(const uint4*)&Hb[(size_t)sB * FH + f8];
#pragma unroll
            for (int i = 0; i < 4; ++i) {
                float2 hA = __bfloat1622float2(cvA.b[i]);
                float2 hB2 = __bfloat1622float2(cvB.b[i]);
                acc[2 * i]     = fmaf(wA, hA.x, acc[2 * i]);
                acc[2 * i + 1] = fmaf(wA, hA.y, acc[2 * i + 1]);
                acc[2 * i]     = fmaf(wB, hB2.x, acc[2 * i]);
                acc[2 * i + 1] = fmaf(wB, hB2.y, acc[2 * i + 1]);
            }
        }
    }
#pragma unroll
    for (int o = 4; o < 64; o <<= 1) d += __shfl_xor(d, o);
#pragma unroll
    for (int i = 0; i < 8; ++i) {
        acc[i] += __shfl_xor(acc[i], 16);
        acc[i] += __shfl_xor(acc[i], 32);
    }
    const float inv = 1.0f / __shfl(d, hC);
    if (es == 0) {
        union { ushort u8[8]; uint4 u; } pk;
#pragma unroll
        for (int i = 0; i < 8; ++i) {
            float v = fmaxf(fmaf(acc[i], inv, bias[f8 + i]), 0.f);
            pk.u8[i] = f2bf_bits(v);
        }
        *(uint4*)&out[(size_t)n * FH + f8] = pk.u;
    }
}

// ---------------------------------------------------------------------------
// Mean pool: one block per graph (batch sorted -> boundaries via binary
// search), LDS tree-reduce, plain stores. Zero atomics, no memset needed.
// ---------------------------------------------------------------------------
__global__ __launch_bounds__(256) void pool_kernel(
    const __hip_bfloat16* __restrict__ X, const int* __restrict__ batch,
    float* __restrict__ sums, int* __restrict__ cnts)
{
    const int g = blockIdx.x;
    const int t = threadIdx.x;
    int a = 0, b = NN;
    while (a < b) { int m = (a + b) >> 1; if (batch[m] < g) a = m + 1; else b = m; }
    const int gs = a;
    b = NN;
    while (a < b) { int m = (a + b) >> 1; if (batch[m] <= g) a = m + 1; else b = m; }
    const int ge = a;

    const int rg = t >> 4;       // row group 0..15
    const int l16 = t & 15;      // 16B feature slot
    float acc[8];
#pragma unroll
    for (int i = 0; i < 8; ++i) acc[i] = 0.f;
    for (int r = gs + rg; r < ge; r += 16) {
        union { uint4 u; __hip_bfloat162 bb[4]; } cv;
        cv.u = *(const uint4*)&X[(size_t)r * FH + l16 * 8];
#pragma unroll
        for (int i = 0; i < 4; ++i) {
            float2 f = __bfloat1622float2(cv.bb[i]);
            acc[2 * i]     += f.x;
            acc[2 * i + 1] += f.y;
        }
    }
    __shared__ float red[16][128];
#pragma unroll
    for (int i = 0; i < 8; ++i) red[rg][l16 * 8 + i] = acc[i];
    __syncthreads();
    if (t < 128) {
        float s = 0.f;
#pragma unroll
        for (int j = 0; j < 16; ++j) s += red[j][t];
        sums[g * FH + t] = s;
    }
    if (t == 0) cnts[g] = ge - gs;
}

__global__ void final_kernel(const float* __restrict__ sums, const int* __restrict__ cnts,
                             const float* __restrict__ wl, const float* __restrict__ bl,
                             float* __restrict__ out)
{
    const int t = threadIdx.x;
    if (t >= NG * OC) return;
    const int g = t / OC, o = t % OC;
    float invc = 1.0f / fmaxf((float)cnts[g], 1.0f);
    float acc = 0.f;
    for (int k = 0; k < FH; ++k)
        acc = fmaf(sums[g * FH + k], wl[k * OC + o], acc);
    out[t] = acc * invc + bl[o];
}

// ---------------------------------------------------------------------------
extern "C" void kernel_launch(void* const* d_in, const int* in_sizes, int n_in,
                              void* d_out, int out_size, void* d_ws, size_t ws_size,
                              hipStream_t stream) {
    const float* x       = (const float*)d_in[0];
    const int*   ei      = (const int*)d_in[1];   // [2, NE]
    const int*   batch   = (const int*)d_in[2];
    const float* W1      = (const float*)d_in[3];
    const float* as1     = (const float*)d_in[4];
    const float* ad1     = (const float*)d_in[5];
    const float* b1      = (const float*)d_in[6];
    const float* W2      = (const float*)d_in[7];
    const float* as2     = (const float*)d_in[8];
    const float* ad2     = (const float*)d_in[9];
    const float* b2      = (const float*)d_in[10];
    const float* wlin    = (const float*)d_in[11];
    const float* blin    = (const float*)d_in[12];
    float* out = (float*)d_out;

    // workspace layout (everything fully rewritten each call -> no memset)
    __hip_bfloat16* hbuf = (__hip_bfloat16*)d_ws;        // NN*FH bf16 (gemm out)
    __hip_bfloat16* abuf = hbuf + (size_t)NN * FH;       // NN*FH bf16 (agg out)
    float* asrc  = (float*)(abuf + (size_t)NN * FH);     // NN*4
    float* adst  = asrc + (size_t)NN * NHEAD;
    float* sums  = adst + (size_t)NN * NHEAD; // NG*FH
    int*   cnts  = (int*)(sums + NG * FH);    // NG
    int* offs    = cnts + NG;                 // NN+1
    int* csrc    = offs + NN + 1;             // ET
    int2* ebuf   = (int2*)(((uintptr_t)(csrc + ET) + 7) & ~(uintptr_t)7); // NE int2
    int* bh      = (int*)(ebuf + NE);         // NBK*HBLK
    int* bsumB   = bh + NBK * HBLK;           // NBK
    int* ebase   = bsumB + NBK;               // NBK+1
    ushort* wt   = (ushort*)(((uintptr_t)(ebase + NBK + 1) + 15) & ~(uintptr_t)15); // 4*WPLANE

    // W pack first (fused kernel's gemm blocks read planes 0,1)
    pack_kernel<<<128, 256, 0, stream>>>(W1, W2, wt);

    // Fused: layer-1 GEMM + bucket histograms (one dispatch)
    fused_gemm_hist_kernel<<<GEMM1_GRID + HBLK, 1024, 0, stream>>>(
        ei, bh, x, wt, as1, ad1, hbuf, asrc, adst);

    scanA_kernel<<<NBK, 256, 0, stream>>>(bh, bsumB);
    scanB_kernel<<<1, 256, 0, stream>>>(bsumB, ebase, offs);
    bucket_scatter_kernel<<<HBLK, 1024, 0, stream>>>(ei, bh, ebase, ebuf);
    bucket_csr_kernel<<<NBK, 256, 0, stream>>>(ebuf, ebase, offs, csrc);

    const int agg_grid = (NN + 3) / 4;

    // Layer 1 aggregation (gemm already done in fused dispatch)
    gat_agg_kernel<<<agg_grid, 256, 0, stream>>>(hbuf, asrc, adst, offs, csrc, b1, abuf);
    // Layer 2
    gemm_att_bf16_kernel<<<GEMM2_GRID, 256, 0, stream>>>(abuf, wt + 2 * WPLANE, as2, ad2, hbuf, asrc, adst);
    gat_agg_kernel<<<agg_grid, 256, 0, stream>>>(hbuf, asrc, adst, offs, csrc, b2, abuf);

    // Pool + final linear
    pool_kernel<<<NG, 256, 0, stream>>>(abuf, batch, sums, cnts);
    final_kernel<<<1, NG * OC, 0, stream>>>(sums, cnts, wlin, blin, out);
}